// Round 1
// 467.074 us; speedup vs baseline: 1.2100x; 1.2100x over previous
//
#include <hip/hip_runtime.h>
#include <math.h>

// RG-LRU: B=4, L=8192, W=1024, H=8, bw=128.
#define NB 4
#define NL 8192
#define NW 1024
#define NH 8
#define BWID 128
#define POWERF 8.0f

#define TM 64               // timesteps per block
#define NRC (NL / TM)       // 128 row-chunks

#define C2 128
#define T2 (NL / C2)        // 64

typedef __attribute__((ext_vector_type(8))) short bf16x8;          // MFMA A/B frag (8 bf16)
typedef __attribute__((ext_vector_type(8))) unsigned short u16x8;  // raw 16B move
typedef __attribute__((ext_vector_type(4))) float f32x4;           // MFMA C/D frag

__device__ __forceinline__ unsigned short bf_hi(float f) {
  return (unsigned short)(__float_as_uint(f) >> 16);  // truncate to bf16
}
__device__ __forceinline__ float bf_f(unsigned short h) {
  return __uint_as_float(((unsigned)h) << 16);
}

// ---------------- prep: W^T in bf16 hi/lo + softplus(a_param) ----------------
// wt layout: [mat(2)][split(2)][h(8)][col(128)][k(128)] ushort (1 MB total).
// Runs once per launch (~1 MB traffic); lets gates stage W with pure copies.
__global__ void prep_kernel(const float* __restrict__ w_in,
                            const float* __restrict__ w_a,
                            const float* __restrict__ a_param,
                            unsigned short* __restrict__ wt,
                            float* __restrict__ sp) {
  const int gtid = blockIdx.x * 256 + threadIdx.x;  // 0..262143
  const int k   = gtid & 127;
  const int col = (gtid >> 7) & 127;
  const int hh  = (gtid >> 14) & 7;
  const int mat = gtid >> 17;
  const float* src = mat ? w_a : w_in;
  const float v = src[((size_t)hh * 128 + k) * 128 + col];  // W[h][k][col]
  const unsigned short hi = bf_hi(v);
  const unsigned short lo = bf_hi(v - bf_f(hi));
  wt[(((size_t)(mat * 2 + 0) * 8 + hh) * 128 + col) * 128 + k] = hi;
  wt[(((size_t)(mat * 2 + 1) * 8 + hh) * 128 + col) * 128 + k] = lo;
  if (gtid < NW) sp[gtid] = log1pf(expf(a_param[gtid]));
}

// ---------------- K1: MFMA block-diag matmuls + gates + a / x_norm ----------
// Block = (b, head, 64 timesteps); 256 threads = 4 waves; wave w owns rows
// [16w,16w+16). Split-bf16 GEMM: z = xh*wh + xh*wl + xl*wh via
// mfma_f32_16x16x32_bf16 (frag = 8 contiguous k per lane-group, one 16B LDS
// read each — m97-verified pattern). LDS rows are 256B with a full
// ((idx&15)<<4) XOR swizzle applied on BOTH write and read (bank-conflict-free
// frag reads). W staged per 32-k tile from the pre-transposed wt buffer.
__global__ __launch_bounds__(256, 2)
void gates_kernel(const float* __restrict__ x,
                  const unsigned short* __restrict__ wt,
                  const float* __restrict__ sp,
                  const float* __restrict__ b_in,
                  const float* __restrict__ b_a,
                  float* __restrict__ a_out,
                  float* __restrict__ xn_out) {
  __shared__ unsigned short sXh[TM * BWID];   // 16 KB  [row][k] swizzled
  __shared__ unsigned short sXl[TM * BWID];   // 16 KB
  __shared__ unsigned short sW[BWID * 128];   // 32 KB  [col][arr(4)][kk(32)] swizzled

  const int blk = blockIdx.x;
  const int rc = blk % NRC;
  const int h  = (blk / NRC) % NH;
  const int b  = blk / (NRC * NH);
  const int tid  = threadIdx.x;
  const int lane = tid & 63;
  const int wid  = tid >> 6;
  const int g  = lane >> 4;   // k-group 0..3
  const int ln = lane & 15;

  char* const pXh = (char*)sXh;
  char* const pXl = (char*)sXl;
  char* const pW  = (char*)sW;

  const size_t xbase = ((size_t)b * NL + (size_t)rc * TM) * NW + h * BWID;

  // ---- stage X as bf16 hi/lo: 1024 chunks of 8 floats, coalesced ----
#pragma unroll
  for (int i = 0; i < 4; ++i) {
    const int chunk = tid + 256 * i;      // 0..1023
    const int row = chunk >> 4;           // 16 chunks/row
    const int k8  = (chunk & 15) * 8;
    const float4 v0 = *(const float4*)(x + xbase + (size_t)row * NW + k8);
    const float4 v1 = *(const float4*)(x + xbase + (size_t)row * NW + k8 + 4);
    const float f[8] = {v0.x, v0.y, v0.z, v0.w, v1.x, v1.y, v1.z, v1.w};
    u16x8 vh, vl;
#pragma unroll
    for (int j = 0; j < 8; ++j) {
      const unsigned short hi = bf_hi(f[j]);
      vh[j] = hi;
      vl[j] = bf_hi(f[j] - bf_f(hi));
    }
    const int off = row * 256 + ((k8 * 2) ^ ((row & 15) << 4));
    *(u16x8*)(pXh + off) = vh;
    *(u16x8*)(pXl + off) = vl;
  }

  f32x4 accx[8], acca[8];
#pragma unroll
  for (int t = 0; t < 8; ++t) {
    accx[t] = (f32x4){0.f, 0.f, 0.f, 0.f};
    acca[t] = (f32x4){0.f, 0.f, 0.f, 0.f};
  }

  const int arow = wid * 16 + ln;                 // A-frag row (timestep)
  const int arsw = (arow & 15) << 4;

#pragma unroll 1
  for (int kt = 0; kt < BWID; kt += 32) {
    __syncthreads();  // X staged (kt=0) / previous W tile consumed (kt>0)
    // ---- stage W k-tile: 2048 16B chunks from wt (L2-resident) ----
#pragma unroll
    for (int i = 0; i < 8; ++i) {
      const int chunk = tid + 256 * i;   // 0..2047
      const int arr = chunk >> 9;        // 0:in_hi 1:in_lo 2:a_hi 3:a_lo
      const int rem = chunk & 511;
      const int col = rem >> 2;
      const int kk8 = (rem & 3) * 8;
      const u16x8 wv = *(const u16x8*)(wt + ((size_t)arr * 8 + h) * 16384 +
                                       (size_t)col * 128 + kt + kk8);
      const int off = col * 256 + ((arr * 64 + kk8 * 2) ^ ((col & 15) << 4));
      *(u16x8*)(pW + off) = wv;
    }
    __syncthreads();

    const int abyte = arow * 256 + (((kt + g * 8) * 2) ^ arsw);
    const bf16x8 Ah = *(const bf16x8*)(pXh + abyte);
    const bf16x8 Al = *(const bf16x8*)(pXl + abyte);
    const int cs = ln << 4;  // (col&15)<<4, ct-independent
    const int gk = g * 16;
#pragma unroll
    for (int ct = 0; ct < 8; ++ct) {
      const int cb = (ct * 16 + ln) * 256;
      const bf16x8 Bih = *(const bf16x8*)(pW + cb + ((0   + gk) ^ cs));
      const bf16x8 Bil = *(const bf16x8*)(pW + cb + ((64  + gk) ^ cs));
      const bf16x8 Bah = *(const bf16x8*)(pW + cb + ((128 + gk) ^ cs));
      const bf16x8 Bal = *(const bf16x8*)(pW + cb + ((192 + gk) ^ cs));
      accx[ct] = __builtin_amdgcn_mfma_f32_16x16x32_bf16(Ah, Bih, accx[ct], 0, 0, 0);
      accx[ct] = __builtin_amdgcn_mfma_f32_16x16x32_bf16(Al, Bih, accx[ct], 0, 0, 0);
      accx[ct] = __builtin_amdgcn_mfma_f32_16x16x32_bf16(Ah, Bil, accx[ct], 0, 0, 0);
      acca[ct] = __builtin_amdgcn_mfma_f32_16x16x32_bf16(Ah, Bah, acca[ct], 0, 0, 0);
      acca[ct] = __builtin_amdgcn_mfma_f32_16x16x32_bf16(Al, Bah, acca[ct], 0, 0, 0);
      acca[ct] = __builtin_amdgcn_mfma_f32_16x16x32_bf16(Ah, Bal, acca[ct], 0, 0, 0);
    }
  }

  // ---- epilogue: C/D layout col=lane&15, row=(lane>>4)*4+reg (m89) ----
#pragma unroll
  for (int ct = 0; ct < 8; ++ct) {
    const int col = ct * 16 + ln;
    const float bi  = b_in[h * BWID + col];
    const float ba  = b_a[h * BWID + col];
    const float spv = sp[h * BWID + col];
#pragma unroll
    for (int r = 0; r < 4; ++r) {
      const int row = wid * 16 + g * 4 + r;
      const float zx = accx[ct][r] + bi;
      const float za = acca[ct][r] + ba;
      const int xoff = row * 256 + ((col * 2) ^ ((row & 15) << 4));
      const float xv = bf_f(*(const unsigned short*)(pXh + xoff)) +
                       bf_f(*(const unsigned short*)(pXl + xoff));
      const float gx = __builtin_amdgcn_rcpf(1.f + __expf(-zx));
      const float ga = __builtin_amdgcn_rcpf(1.f + __expf(-za));
      const float la = -POWERF * ga * spv;
      const float av = __expf(la);
      const float asq = __expf(2.f * la);
      const float xn = xv * gx * sqrtf(fmaxf(1.f - asq, 0.f));
      const size_t o = xbase + (size_t)row * NW + col;
      a_out[o]  = av;
      xn_out[o] = xn;
    }
  }
}

// ---------------- chunked linear scan: h_t = a_t*h + x_t (unchanged) --------
__global__ void scan_local(const float* __restrict__ a_ws,
                           const float* __restrict__ xn,
                           float* __restrict__ Aprod,
                           float* __restrict__ hend) {
  const int blk = blockIdx.x;
  const int c = blk % C2;
  const int b = blk / C2;
  const int w2 = threadIdx.x;
  const size_t base = ((size_t)b * NL + (size_t)c * T2) * NW + 2 * w2;
  float h0 = 0.f, h1 = 0.f, A0 = 1.f, A1 = 1.f;
#pragma unroll 4
  for (int t = 0; t < T2; ++t) {
    const float2 a  = *(const float2*)(a_ws + base + (size_t)t * NW);
    const float2 xv = *(const float2*)(xn   + base + (size_t)t * NW);
    h0 = fmaf(a.x, h0, xv.x); A0 *= a.x;
    h1 = fmaf(a.y, h1, xv.y); A1 *= a.y;
  }
  const size_t o = ((size_t)c * NB + b) * NW + 2 * w2;
  *(float2*)(Aprod + o) = make_float2(A0, A1);
  *(float2*)(hend  + o) = make_float2(h0, h1);
}

__global__ void scan_carry(const float* __restrict__ Aprod,
                           const float* __restrict__ hend,
                           float* __restrict__ hinit) {
  const int tid = blockIdx.x * blockDim.x + threadIdx.x;
  const int b  = tid >> 8;
  const int w4 = tid & 255;
  float c0 = 0.f, c1 = 0.f, c2 = 0.f, c3 = 0.f;
  for (int c = 0; c < C2; ++c) {
    const size_t o = ((size_t)c * NB + b) * NW + 4 * w4;
    *(float4*)(hinit + o) = make_float4(c0, c1, c2, c3);
    const float4 A  = *(const float4*)(Aprod + o);
    const float4 he = *(const float4*)(hend + o);
    c0 = fmaf(A.x, c0, he.x);
    c1 = fmaf(A.y, c1, he.y);
    c2 = fmaf(A.z, c2, he.z);
    c3 = fmaf(A.w, c3, he.w);
  }
}

__global__ void scan_final(const float* __restrict__ a_ws,
                           const float* __restrict__ hinit,
                           float* __restrict__ out) {
  const int blk = blockIdx.x;
  const int c = blk % C2;
  const int b = blk / C2;
  const int w2 = threadIdx.x;
  const size_t hidx = ((size_t)c * NB + b) * NW + 2 * w2;
  const float2 hi = *(const float2*)(hinit + hidx);
  float h0 = hi.x, h1 = hi.y;
  const size_t base = ((size_t)b * NL + (size_t)c * T2) * NW + 2 * w2;
#pragma unroll 4
  for (int t = 0; t < T2; ++t) {
    const size_t o = base + (size_t)t * NW;
    const float2 a  = *(const float2*)(a_ws + o);
    const float2 xv = *(const float2*)(out + o);
    h0 = fmaf(a.x, h0, xv.x);
    h1 = fmaf(a.y, h1, xv.y);
    *(float2*)(out + o) = make_float2(h0, h1);
  }
}

extern "C" void kernel_launch(void* const* d_in, const int* in_sizes, int n_in,
                              void* d_out, int out_size, void* d_ws, size_t ws_size,
                              hipStream_t stream) {
  const float* x       = (const float*)d_in[0];
  const float* a_param = (const float*)d_in[1];
  const float* w_in    = (const float*)d_in[2];
  const float* b_in    = (const float*)d_in[3];
  const float* w_a     = (const float*)d_in[4];
  const float* b_a     = (const float*)d_in[5];
  float* out = (float*)d_out;

  // Workspace: a array (128 MB) + 3 carry arrays (2 MB each).
  // wt (1 MB) + sp (4 KB) alias the Aprod region: they are only live between
  // prep/gates; scan_local fully rewrites Aprod afterwards (stream-ordered).
  float* a_ws  = (float*)d_ws;
  float* Aprod = a_ws + (size_t)NB * NL * NW;
  float* hend  = Aprod + (size_t)C2 * NB * NW;
  float* hinit = hend  + (size_t)C2 * NB * NW;
  unsigned short* wt = (unsigned short*)Aprod;          // 2*2*8*128*128 = 1 MB
  float* sp = (float*)(wt + (size_t)2 * 2 * 8 * 128 * 128);

  prep_kernel<<<1024, 256, 0, stream>>>(w_in, w_a, a_param, wt, sp);
  gates_kernel<<<NB * NH * NRC, 256, 0, stream>>>(
      x, wt, sp, b_in, b_a, a_ws, out);
  scan_local<<<NB * C2, 512, 0, stream>>>(a_ws, out, Aprod, hend);
  scan_carry<<<4, 256, 0, stream>>>(Aprod, hend, hinit);
  scan_final<<<NB * C2, 512, 0, stream>>>(a_ws, hinit, out);
}

// Round 4
// 429.247 us; speedup vs baseline: 1.3167x; 1.0881x over previous
//
#include <hip/hip_runtime.h>
#include <math.h>

// RG-LRU: B=4, L=8192, W=1024, H=8, bw=128.
#define NB 4
#define NL 8192
#define NW 1024
#define NH 8
#define BWID 128
#define POWERF 8.0f

#define TM 64               // timesteps per gates block == scan chunk size
#define NRC (NL / TM)       // 128 row-chunks == C2

#define C2 128
#define T2 (NL / C2)        // 64

typedef __attribute__((ext_vector_type(8))) short bf16x8;          // MFMA A/B frag
typedef __attribute__((ext_vector_type(8))) unsigned short u16x8;  // raw 16B move
typedef __attribute__((ext_vector_type(4))) float f32x4;           // MFMA C/D frag

__device__ __forceinline__ unsigned short bf_hi(float f) {
  return (unsigned short)(__float_as_uint(f) >> 16);  // truncate to bf16
}
__device__ __forceinline__ float bf_f(unsigned short h) {
  return __uint_as_float(((unsigned)h) << 16);
}

// ---------------- prep: W^T in bf16 hi/lo + softplus(a_param) ----------------
// wt layout: [mat(2)][split(2)][h(8)][col(128)][k(128)] ushort (1 MB total).
__global__ void prep_kernel(const float* __restrict__ w_in,
                            const float* __restrict__ w_a,
                            const float* __restrict__ a_param,
                            unsigned short* __restrict__ wt,
                            float* __restrict__ sp) {
  const int gtid = blockIdx.x * 256 + threadIdx.x;  // 0..262143
  const int k   = gtid & 127;
  const int col = (gtid >> 7) & 127;
  const int hh  = (gtid >> 14) & 7;
  const int mat = gtid >> 17;
  const float* src = mat ? w_a : w_in;
  const float v = src[((size_t)hh * 128 + k) * 128 + col];  // W[h][k][col]
  const unsigned short hi = bf_hi(v);
  const unsigned short lo = bf_hi(v - bf_f(hi));
  wt[(((size_t)(mat * 2 + 0) * 8 + hh) * 128 + col) * 128 + k] = hi;
  wt[(((size_t)(mat * 2 + 1) * 8 + hh) * 128 + col) * 128 + k] = lo;
  if (gtid < NW) sp[gtid] = log1pf(expf(a_param[gtid]));
}

// ---------------- K1: MFMA gates + fused chunk-local scan -------------------
// Block = (b, head, 64 timesteps) == one scan chunk. 4 waves; wave w owns a
// 32-row x 64-col output sub-tile (wr=w>>1, wc=w&1) -> B-frag LDS reads per
// k-tile halved vs 16x128 split. Next W k-tile is register-prefetched before
// the current tile's MFMAs (2-phase: load latency hides under compute).
// Epilogue: a/xn staged to LDS f32 (swizzle ^((row&7)<<4) both sides), then
// waves 0-1 run the per-column local scan (== old scan_local, bit-identical
// fmaf order) while waves 2-3 do coalesced float4 global stores from LDS.
__global__ __launch_bounds__(256, 2)
void gates_kernel(const float* __restrict__ x,
                  const unsigned short* __restrict__ wt,
                  const float* __restrict__ sp,
                  const float* __restrict__ b_in,
                  const float* __restrict__ b_a,
                  float* __restrict__ a_out,
                  float* __restrict__ xn_out,
                  float* __restrict__ Aprod,
                  float* __restrict__ hend) {
  __shared__ char smem[65536];
  char* const pXh = smem;            // 16 KB u16 [64][128] swz ((row&15)<<4)
  char* const pXl = smem + 16384;    // 16 KB
  char* const pW  = smem + 32768;    // 32 KB u16 [col(128)][arr(4)][kk(32)] swz
  // post-MFMA f32 overlays, swz ((row&7)<<4):
  char* const pA  = smem + 32768;    // 32 KB f32 [64][128]  (over sW)
  char* const pXn = smem;            // 32 KB f32 [64][128]  (over sXh+sXl)

  const int blk = blockIdx.x;
  const int rc = blk % NRC;
  const int h  = (blk / NRC) % NH;
  const int b  = blk / (NRC * NH);
  const int tid  = threadIdx.x;
  const int lane = tid & 63;
  const int wid  = tid >> 6;
  const int g  = lane >> 4;   // k-group 0..3
  const int ln = lane & 15;
  const int wr = wid >> 1;    // row half (32 rows)
  const int wc = wid & 1;     // col half (64 cols)

  const size_t xbase = ((size_t)b * NL + (size_t)rc * TM) * NW + h * BWID;

  // ---- W prefetch addressing (8 chunks/thread, kt-independent) ----
  int wsoff[8], wdoff[8];
#pragma unroll
  for (int i = 0; i < 8; ++i) {
    const int chunk = tid + 256 * i;   // 0..2047
    const int arr = chunk >> 9;        // 0:in_hi 1:in_lo 2:a_hi 3:a_lo
    const int rem = chunk & 511;
    const int col = rem >> 2;
    const int kk8 = (rem & 3) * 8;
    wsoff[i] = (arr * 8 + h) * 16384 + col * 128 + kk8;  // + kt at use
    wdoff[i] = col * 256 + ((arr * 64 + kk8 * 2) ^ ((col & 15) << 4));
  }
  u16x8 wreg[8];
#pragma unroll
  for (int i = 0; i < 8; ++i) wreg[i] = *(const u16x8*)(wt + wsoff[i]);  // kt=0

  // ---- stage X as bf16 hi/lo (overlaps W[0] loads) ----
#pragma unroll
  for (int i = 0; i < 4; ++i) {
    const int chunk = tid + 256 * i;      // 0..1023
    const int row = chunk >> 4;
    const int k8  = (chunk & 15) * 8;
    const float4 v0 = *(const float4*)(x + xbase + (size_t)row * NW + k8);
    const float4 v1 = *(const float4*)(x + xbase + (size_t)row * NW + k8 + 4);
    const float f[8] = {v0.x, v0.y, v0.z, v0.w, v1.x, v1.y, v1.z, v1.w};
    u16x8 vh, vl;
#pragma unroll
    for (int j = 0; j < 8; ++j) {
      const unsigned short hi = bf_hi(f[j]);
      vh[j] = hi;
      vl[j] = bf_hi(f[j] - bf_f(hi));
    }
    const int off = row * 256 + ((k8 * 2) ^ ((row & 15) << 4));
    *(u16x8*)(pXh + off) = vh;
    *(u16x8*)(pXl + off) = vl;
  }
  __syncthreads();                 // X staged; sW untouched
#pragma unroll
  for (int i = 0; i < 8; ++i) *(u16x8*)(pW + wdoff[i]) = wreg[i];  // W[0]->LDS

  f32x4 accx[2][4], acca[2][4];
#pragma unroll
  for (int rt = 0; rt < 2; ++rt)
#pragma unroll
    for (int ct = 0; ct < 4; ++ct) {
      accx[rt][ct] = (f32x4){0.f, 0.f, 0.f, 0.f};
      acca[rt][ct] = (f32x4){0.f, 0.f, 0.f, 0.f};
    }

#pragma unroll 1
  for (int kt = 0; kt < BWID; kt += 32) {
    if (kt < 96) {                  // issue next-tile loads (latency hidden)
#pragma unroll
      for (int i = 0; i < 8; ++i)
        wreg[i] = *(const u16x8*)(wt + wsoff[i] + kt + 32);
    }
    __syncthreads();                // current W tile visible in sW

    bf16x8 Ah[2], Al[2];
#pragma unroll
    for (int rt = 0; rt < 2; ++rt) {
      const int arow = wr * 32 + rt * 16 + ln;
      const int abyte = arow * 256 + (((kt + g * 8) * 2) ^ ((arow & 15) << 4));
      Ah[rt] = *(const bf16x8*)(pXh + abyte);
      Al[rt] = *(const bf16x8*)(pXl + abyte);
    }
    const int cs = ln << 4;
    const int gk = g * 16;
#pragma unroll
    for (int ct = 0; ct < 4; ++ct) {
      const int cb = (wc * 64 + ct * 16 + ln) * 256;
      const bf16x8 Bih = *(const bf16x8*)(pW + cb + ((0   + gk) ^ cs));
      const bf16x8 Bil = *(const bf16x8*)(pW + cb + ((64  + gk) ^ cs));
      const bf16x8 Bah = *(const bf16x8*)(pW + cb + ((128 + gk) ^ cs));
      const bf16x8 Bal = *(const bf16x8*)(pW + cb + ((192 + gk) ^ cs));
#pragma unroll
      for (int rt = 0; rt < 2; ++rt) {
        accx[rt][ct] = __builtin_amdgcn_mfma_f32_16x16x32_bf16(Ah[rt], Bih, accx[rt][ct], 0, 0, 0);
        accx[rt][ct] = __builtin_amdgcn_mfma_f32_16x16x32_bf16(Al[rt], Bih, accx[rt][ct], 0, 0, 0);
        accx[rt][ct] = __builtin_amdgcn_mfma_f32_16x16x32_bf16(Ah[rt], Bil, accx[rt][ct], 0, 0, 0);
        acca[rt][ct] = __builtin_amdgcn_mfma_f32_16x16x32_bf16(Ah[rt], Bah, acca[rt][ct], 0, 0, 0);
        acca[rt][ct] = __builtin_amdgcn_mfma_f32_16x16x32_bf16(Al[rt], Bah, acca[rt][ct], 0, 0, 0);
        acca[rt][ct] = __builtin_amdgcn_mfma_f32_16x16x32_bf16(Ah[rt], Bal, acca[rt][ct], 0, 0, 0);
      }
    }
    __syncthreads();                // frag reads of this tile done
    if (kt < 96) {
#pragma unroll
      for (int i = 0; i < 8; ++i) *(u16x8*)(pW + wdoff[i]) = wreg[i];
    }
  }
  // after last iteration's barrier: sW free for pA overlay.

  // ---- epilogue stage 1: gates; av -> pA(LDS); xn kept in regs ----
  float xn_sav[2][4][4];
#pragma unroll
  for (int ct = 0; ct < 4; ++ct) {
    const int col = wc * 64 + ct * 16 + ln;
    const float bi  = b_in[h * BWID + col];
    const float ba  = b_a[h * BWID + col];
    const float spv = sp[h * BWID + col];
#pragma unroll
    for (int rt = 0; rt < 2; ++rt) {
#pragma unroll
      for (int r = 0; r < 4; ++r) {
        const int row = wr * 32 + rt * 16 + g * 4 + r;  // C/D layout (m89)
        const float zx = accx[rt][ct][r] + bi;
        const float za = acca[rt][ct][r] + ba;
        const int xoff = row * 256 + ((col * 2) ^ ((row & 15) << 4));
        const float xv = bf_f(*(const unsigned short*)(pXh + xoff)) +
                         bf_f(*(const unsigned short*)(pXl + xoff));
        const float gx = __builtin_amdgcn_rcpf(1.f + __expf(-zx));
        const float ga = __builtin_amdgcn_rcpf(1.f + __expf(-za));
        const float la = -POWERF * ga * spv;
        const float av = __expf(la);
        const float asq = __expf(2.f * la);
        const float xn = xv * gx * sqrtf(fmaxf(1.f - asq, 0.f));
        *(float*)(pA + row * 512 + ((col * 4) ^ ((row & 7) << 4))) = av;
        xn_sav[rt][ct][r] = xn;
      }
    }
  }
  __syncthreads();                  // all X (u16) reads done
  // ---- stage 2: xn -> pXn (over X area) ----
#pragma unroll
  for (int ct = 0; ct < 4; ++ct) {
    const int col = wc * 64 + ct * 16 + ln;
#pragma unroll
    for (int rt = 0; rt < 2; ++rt) {
#pragma unroll
      for (int r = 0; r < 4; ++r) {
        const int row = wr * 32 + rt * 16 + g * 4 + r;
        *(float*)(pXn + row * 512 + ((col * 4) ^ ((row & 7) << 4))) =
            xn_sav[rt][ct][r];
      }
    }
  }
  __syncthreads();
  // ---- stage 3: waves 0-1 scan columns; waves 2-3 store a/xn coalesced ----
  if (tid < 128) {
    const int w = tid;
    float hh = 0.f, A = 1.f;
#pragma unroll 4
    for (int t = 0; t < TM; ++t) {
      const int so = ((w * 4) ^ ((t & 7) << 4)) + t * 512;
      const float a  = *(const float*)(pA + so);
      const float xv = *(const float*)(pXn + so);
      hh = fmaf(a, hh, xv);   // same order as old scan_local -> bit-identical
      A *= a;
    }
    const size_t o = ((size_t)rc * NB + b) * NW + h * BWID + w;
    Aprod[o] = A;
    hend[o]  = hh;
  } else {
    const int t2 = tid - 128;
#pragma unroll
    for (int i = 0; i < 16; ++i) {
      const int idx = t2 + 128 * i;         // 0..2047 float4 chunks
      const int row = idx >> 5;
      const int c4  = (idx & 31) * 4;
      const int lo  = row * 512 + ((c4 * 4) ^ ((row & 7) << 4));
      const float4 av  = *(const float4*)(pA + lo);
      const float4 xnv = *(const float4*)(pXn + lo);
      *(float4*)(a_out  + xbase + (size_t)row * NW + c4) = av;
      *(float4*)(xn_out + xbase + (size_t)row * NW + c4) = xnv;
    }
  }
}

// K3: serial prefix over the C2 chunk carries -> exclusive h_init per chunk.
__global__ void scan_carry(const float* __restrict__ Aprod,
                           const float* __restrict__ hend,
                           float* __restrict__ hinit) {
  const int tid = blockIdx.x * blockDim.x + threadIdx.x; // 0..1023
  const int b  = tid >> 8;
  const int w4 = tid & 255;
  float c0 = 0.f, c1 = 0.f, c2 = 0.f, c3 = 0.f;
  for (int c = 0; c < C2; ++c) {
    const size_t o = ((size_t)c * NB + b) * NW + 4 * w4;
    *(float4*)(hinit + o) = make_float4(c0, c1, c2, c3); // exclusive
    const float4 A  = *(const float4*)(Aprod + o);
    const float4 he = *(const float4*)(hend + o);
    c0 = fmaf(A.x, c0, he.x);
    c1 = fmaf(A.y, c1, he.y);
    c2 = fmaf(A.z, c2, he.z);
    c3 = fmaf(A.w, c3, he.w);
  }
}

// K4: re-scan each chunk from its h_init, write output in place over x_norm.
__global__ void scan_final(const float* __restrict__ a_ws,
                           const float* __restrict__ hinit,
                           float* __restrict__ out) {
  const int blk = blockIdx.x;
  const int c = blk % C2;
  const int b = blk / C2;
  const int w2 = threadIdx.x;
  const size_t hidx = ((size_t)c * NB + b) * NW + 2 * w2;
  const float2 hi = *(const float2*)(hinit + hidx);
  float h0 = hi.x, h1 = hi.y;
  const size_t base = ((size_t)b * NL + (size_t)c * T2) * NW + 2 * w2;
#pragma unroll 4
  for (int t = 0; t < T2; ++t) {
    const size_t o = base + (size_t)t * NW;
    const float2 a  = *(const float2*)(a_ws + o);
    const float2 xv = *(const float2*)(out + o);
    h0 = fmaf(a.x, h0, xv.x);
    h1 = fmaf(a.y, h1, xv.y);
    *(float2*)(out + o) = make_float2(h0, h1);
  }
}

extern "C" void kernel_launch(void* const* d_in, const int* in_sizes, int n_in,
                              void* d_out, int out_size, void* d_ws, size_t ws_size,
                              hipStream_t stream) {
  const float* x       = (const float*)d_in[0];
  const float* a_param = (const float*)d_in[1];
  const float* w_in    = (const float*)d_in[2];
  const float* b_in    = (const float*)d_in[3];
  const float* w_a     = (const float*)d_in[4];
  const float* b_a     = (const float*)d_in[5];
  float* out = (float*)d_out;

  // Workspace: a array (128 MB) + 3 carry arrays (2 MB each).
  // wt (1 MB) + sp (4 KB) alias the hinit region: hinit is written by
  // scan_carry only AFTER gates has consumed wt (stream-ordered).
  float* a_ws  = (float*)d_ws;
  float* Aprod = a_ws + (size_t)NB * NL * NW;
  float* hend  = Aprod + (size_t)C2 * NB * NW;
  float* hinit = hend  + (size_t)C2 * NB * NW;
  unsigned short* wt = (unsigned short*)hinit;          // 1 MB < 2 MB region
  float* sp = (float*)(wt + (size_t)2 * 2 * 8 * 128 * 128);

  prep_kernel<<<1024, 256, 0, stream>>>(w_in, w_a, a_param, wt, sp);
  gates_kernel<<<NB * NH * NRC, 256, 0, stream>>>(
      x, wt, sp, b_in, b_a, a_ws, out, Aprod, hend);
  scan_carry<<<4, 256, 0, stream>>>(Aprod, hend, hinit);
  scan_final<<<NB * C2, 512, 0, stream>>>(a_ws, hinit, out);
}